// Round 1
// baseline (128.224 us; speedup 1.0000x reference)
//
#include <hip/hip_runtime.h>
#include <hip/hip_bf16.h>
#include <stdint.h>

#define M_DIM 8192
#define N_DIM 2048
#define K_DIM 2048

typedef __attribute__((ext_vector_type(8))) short bf16x8;
typedef __attribute__((ext_vector_type(8))) short short8;
typedef __attribute__((ext_vector_type(4))) float f32x4;

static __device__ __forceinline__ unsigned short f2bf(float f) {
  union { float f; unsigned u; } a; a.f = f;
  unsigned u = a.u;
  u += 0x7FFFu + ((u >> 16) & 1u);   // round-to-nearest-even
  return (unsigned short)(u >> 16);
}

static __device__ __forceinline__ void async16(void* lds, const void* g) {
  __builtin_amdgcn_global_load_lds(
      (const __attribute__((address_space(1))) unsigned int*)g,
      (__attribute__((address_space(3))) unsigned int*)lds, 16, 0, 0);
}

// ---- kernel 1: extract W[:,0] into contiguous buffer ----
__global__ __launch_bounds__(256) void k_wcol(const float* __restrict__ W,
                                              float* __restrict__ wcol) {
  int k = blockIdx.x * 256 + threadIdx.x;
  if (k < K_DIM) wcol[k] = W[(size_t)k * N_DIM];
}

// ---- kernel 2: convert X fp32->bf16, fused fp64 row-dot with W[:,0] -> adj ----
__global__ __launch_bounds__(256) void k_convX(const float* __restrict__ X,
    const float* __restrict__ wcol, const float* __restrict__ b,
    unsigned short* __restrict__ Xb, float* __restrict__ adj) {
  const int m = blockIdx.x;
  const int t = threadIdx.x;
  const float4* xr = (const float4*)(X + (size_t)m * K_DIM);
  const float4* wc = (const float4*)wcol;
  float4 x0 = xr[2 * t], x1 = xr[2 * t + 1];
  float4 w0 = wc[2 * t], w1 = wc[2 * t + 1];
  short8 o;
  o[0] = (short)f2bf(x0.x); o[1] = (short)f2bf(x0.y);
  o[2] = (short)f2bf(x0.z); o[3] = (short)f2bf(x0.w);
  o[4] = (short)f2bf(x1.x); o[5] = (short)f2bf(x1.y);
  o[6] = (short)f2bf(x1.z); o[7] = (short)f2bf(x1.w);
  *(short8*)(Xb + (size_t)m * K_DIM + t * 8) = o;
  // fp64 partial dot for the row condition (bf16 error would flip rows)
  double s = (double)x0.x * w0.x + (double)x0.y * w0.y +
             (double)x0.z * w0.z + (double)x0.w * w0.w +
             (double)x1.x * w1.x + (double)x1.y * w1.y +
             (double)x1.z * w1.z + (double)x1.w * w1.w;
  #pragma unroll
  for (int off = 32; off > 0; off >>= 1) s += __shfl_down(s, off, 64);
  __shared__ double red[4];
  if ((t & 63) == 0) red[t >> 6] = s;
  __syncthreads();
  if (t == 0) {
    double tot = red[0] + red[1] + red[2] + red[3] + (double)b[0];
    adj[m] = (tot > 0.5) ? 1.0f : -1.0f;
  }
}

// ---- kernel 3: convert + transpose W [K][N] -> Wt [N][K] bf16 ----
__global__ __launch_bounds__(256) void k_transW(const float* __restrict__ W,
                                                unsigned short* __restrict__ Wt) {
  __shared__ float tile[64][65];
  const int bx = blockIdx.x & 31;   // n-tile (N/64 = 32)
  const int by = blockIdx.x >> 5;   // k-tile (K/64 = 32)
  const int n0 = bx * 64, k0 = by * 64;
  const int t = threadIdx.x;
  #pragma unroll
  for (int i = 0; i < 16; ++i) {
    int lin = i * 256 + t;
    int r = lin >> 6, c = lin & 63;
    tile[r][c] = W[(size_t)(k0 + r) * N_DIM + n0 + c];
  }
  __syncthreads();
  #pragma unroll
  for (int i = 0; i < 16; ++i) {
    int lin = i * 256 + t;
    int r = lin >> 6, c = lin & 63;   // r: n index, c: k index
    Wt[(size_t)(n0 + r) * K_DIM + k0 + c] = f2bf(tile[c][r]);
  }
}

// ---- kernel 4: bf16 MFMA GEMM, 128x128 tile, BK=32, m97 structure ----
__global__ __launch_bounds__(256) void k_gemm(
    const unsigned short* __restrict__ A,   // Xb [M][K] bf16
    const unsigned short* __restrict__ B,   // Wt [N][K] bf16
    const float* __restrict__ bias,
    const float* __restrict__ adj,
    float* __restrict__ out) {
  __shared__ unsigned short Al[128 * 32];
  __shared__ unsigned short Bl[128 * 32];
  const int t = threadIdx.x;
  const int w = t >> 6, l = t & 63;
  const int bm = blockIdx.x >> 4, bn = blockIdx.x & 15;  // N/128 = 16
  const int m0 = bm * 128, n0 = bn * 128;
  const int wr = w >> 1, wc = w & 1;     // wave -> 64x64 sub-tile
  const int r = l & 15, q = l >> 4;

  f32x4 acc[4][4] = {};

  for (int kt = 0; kt < K_DIM / 32; ++kt) {
    const int k0 = kt * 32;
    #pragma unroll
    for (int j = 0; j < 2; ++j) {
      const int c = j * 256 + t;
      const int row = c >> 2, kc = (c & 3) * 8;
      // LDS dest is wave-uniform base + lane*16B (linear layout)
      async16(&Al[(size_t)(j * 256 + (w << 6)) * 8],
              &A[(size_t)(m0 + row) * K_DIM + k0 + kc]);
      async16(&Bl[(size_t)(j * 256 + (w << 6)) * 8],
              &B[(size_t)(n0 + row) * K_DIM + k0 + kc]);
    }
    __syncthreads();
    bf16x8 af[4], bfv[4];
    const int kk = q * 8;
    #pragma unroll
    for (int mi = 0; mi < 4; ++mi)
      af[mi] = *(const bf16x8*)&Al[(wr * 64 + mi * 16 + r) * 32 + kk];
    #pragma unroll
    for (int ni = 0; ni < 4; ++ni)
      bfv[ni] = *(const bf16x8*)&Bl[(wc * 64 + ni * 16 + r) * 32 + kk];
    #pragma unroll
    for (int mi = 0; mi < 4; ++mi)
      #pragma unroll
      for (int ni = 0; ni < 4; ++ni)
        acc[mi][ni] = __builtin_amdgcn_mfma_f32_16x16x32_bf16(
            af[mi], bfv[ni], acc[mi][ni], 0, 0, 0);
    __syncthreads();
  }

  // epilogue: bias + per-row +/-1, C/D layout col=l&15, row=q*4+reg
  #pragma unroll
  for (int mi = 0; mi < 4; ++mi) {
    const int rowbase = m0 + wr * 64 + mi * 16 + q * 4;
    float adjv[4];
    #pragma unroll
    for (int j = 0; j < 4; ++j) adjv[j] = adj[rowbase + j];
    #pragma unroll
    for (int ni = 0; ni < 4; ++ni) {
      const int col = n0 + wc * 64 + ni * 16 + r;
      const float bv = bias[col];
      #pragma unroll
      for (int j = 0; j < 4; ++j)
        out[(size_t)(rowbase + j) * N_DIM + col] = acc[mi][ni][j] + bv + adjv[j];
    }
  }
}

// ---- fallback path (ws too small): fp32 LDS-tiled GEMM + row adjust ----
__global__ __launch_bounds__(256) void k_gemm_f32(const float* __restrict__ X,
    const float* __restrict__ W, const float* __restrict__ b,
    float* __restrict__ out) {
  __shared__ float As[16][16];
  __shared__ float Bs[16][17];
  const int bn = blockIdx.x & 127, bm = blockIdx.x >> 7;
  const int tx = threadIdx.x & 15, ty = threadIdx.x >> 4;
  const int row = bm * 16 + ty, col = bn * 16 + tx;
  float acc = 0.f;
  for (int k0 = 0; k0 < K_DIM; k0 += 16) {
    As[ty][tx] = X[(size_t)row * K_DIM + k0 + tx];
    Bs[ty][tx] = W[(size_t)(k0 + ty) * N_DIM + col];
    __syncthreads();
    #pragma unroll
    for (int kk = 0; kk < 16; ++kk) acc += As[ty][kk] * Bs[kk][tx];
    __syncthreads();
  }
  out[(size_t)row * N_DIM + col] = acc + b[col];
}

__global__ __launch_bounds__(256) void k_rowadj(float* __restrict__ out) {
  const int m = blockIdx.x;
  const float c0 = out[(size_t)m * N_DIM];
  __syncthreads();
  const float a = (c0 > 0.5f) ? 1.0f : -1.0f;
  for (int n = threadIdx.x; n < N_DIM; n += 256)
    out[(size_t)m * N_DIM + n] += a;
}

extern "C" void kernel_launch(void* const* d_in, const int* in_sizes, int n_in,
                              void* d_out, int out_size, void* d_ws, size_t ws_size,
                              hipStream_t stream) {
  const float* X = (const float*)d_in[0];
  const float* W = (const float*)d_in[1];
  const float* b = (const float*)d_in[2];
  float* out = (float*)d_out;

  const size_t XB_OFF   = 0;
  const size_t WT_OFF   = (size_t)M_DIM * K_DIM * 2;        // 32 MB
  const size_t ADJ_OFF  = WT_OFF + (size_t)N_DIM * K_DIM * 2;
  const size_t WCOL_OFF = ADJ_OFF + (size_t)M_DIM * 4;
  const size_t NEED     = WCOL_OFF + (size_t)K_DIM * 4;     // ~40 MB

  if (ws_size >= NEED) {
    unsigned short* Xb  = (unsigned short*)((char*)d_ws + XB_OFF);
    unsigned short* Wt  = (unsigned short*)((char*)d_ws + WT_OFF);
    float* adj  = (float*)((char*)d_ws + ADJ_OFF);
    float* wcol = (float*)((char*)d_ws + WCOL_OFF);
    k_wcol<<<dim3(8), dim3(256), 0, stream>>>(W, wcol);
    k_convX<<<dim3(M_DIM), dim3(256), 0, stream>>>(X, wcol, b, Xb, adj);
    k_transW<<<dim3(1024), dim3(256), 0, stream>>>(W, Wt);
    k_gemm<<<dim3((M_DIM / 128) * (N_DIM / 128)), dim3(256), 0, stream>>>(
        Xb, Wt, b, adj, out);
  } else {
    k_gemm_f32<<<dim3((M_DIM / 16) * (N_DIM / 16)), dim3(256), 0, stream>>>(
        X, W, b, out);
    k_rowadj<<<dim3(M_DIM), dim3(256), 0, stream>>>(out);
  }
}

// Round 3
// 100.536 us; speedup vs baseline: 1.2754x; 1.2754x over previous
//
#include <hip/hip_runtime.h>
#include <hip/hip_bf16.h>
#include <stdint.h>

#define M_DIM 8192
#define N_DIM 2048
#define K_DIM 2048

typedef __attribute__((ext_vector_type(8))) short bf16x8;
typedef __attribute__((ext_vector_type(8))) short short8;
typedef __attribute__((ext_vector_type(4))) float f32x4;

static __device__ __forceinline__ unsigned short f2bf(float f) {
  union { float f; unsigned u; } a; a.f = f;
  unsigned u = a.u;
  u += 0x7FFFu + ((u >> 16) & 1u);   // round-to-nearest-even
  return (unsigned short)(u >> 16);
}

static __device__ __forceinline__ void async16(void* lds, const void* g) {
  __builtin_amdgcn_global_load_lds(
      (const __attribute__((address_space(1))) unsigned int*)g,
      (__attribute__((address_space(3))) unsigned int*)lds, 16, 0, 0);
}

#define BAR()                                \
  do {                                       \
    asm volatile("" ::: "memory");           \
    __builtin_amdgcn_s_barrier();            \
    asm volatile("" ::: "memory");           \
  } while (0)
#define VMCNT(n) asm volatile("s_waitcnt vmcnt(" #n ")" ::: "memory")

// ---- kernel 1: extract W[:,0] ----
__global__ __launch_bounds__(256) void k_wcol(const float* __restrict__ W,
                                              float* __restrict__ wcol) {
  int k = blockIdx.x * 256 + threadIdx.x;
  if (k < K_DIM) wcol[k] = W[(size_t)k * N_DIM];
}

// ---- kernel 2: X fp32->bf16 + fused fp64 row-dot with W[:,0] -> adj ----
__global__ __launch_bounds__(256) void k_convX(const float* __restrict__ X,
    const float* __restrict__ wcol, const float* __restrict__ b,
    unsigned short* __restrict__ Xb, float* __restrict__ adj) {
  const int m = blockIdx.x;
  const int t = threadIdx.x;
  const float4* xr = (const float4*)(X + (size_t)m * K_DIM);
  const float4* wc = (const float4*)wcol;
  float4 x0 = xr[2 * t], x1 = xr[2 * t + 1];
  float4 w0 = wc[2 * t], w1 = wc[2 * t + 1];
  short8 o;
  o[0] = (short)f2bf(x0.x); o[1] = (short)f2bf(x0.y);
  o[2] = (short)f2bf(x0.z); o[3] = (short)f2bf(x0.w);
  o[4] = (short)f2bf(x1.x); o[5] = (short)f2bf(x1.y);
  o[6] = (short)f2bf(x1.z); o[7] = (short)f2bf(x1.w);
  *(short8*)(Xb + (size_t)m * K_DIM + t * 8) = o;
  double s = (double)x0.x * w0.x + (double)x0.y * w0.y +
             (double)x0.z * w0.z + (double)x0.w * w0.w +
             (double)x1.x * w1.x + (double)x1.y * w1.y +
             (double)x1.z * w1.z + (double)x1.w * w1.w;
  #pragma unroll
  for (int off = 32; off > 0; off >>= 1) s += __shfl_down(s, off, 64);
  __shared__ double red[4];
  if ((t & 63) == 0) red[t >> 6] = s;
  __syncthreads();
  if (t == 0) {
    double tot = red[0] + red[1] + red[2] + red[3] + (double)b[0];
    adj[m] = (tot > 0.5) ? 1.0f : -1.0f;
  }
}

// ---- kernel 3: convert + transpose W [K][N] -> Wt [N][K] bf16 ----
__global__ __launch_bounds__(256) void k_transW(const float* __restrict__ W,
                                                unsigned short* __restrict__ Wt) {
  __shared__ float tile[64][65];
  const int bx = blockIdx.x & 31;
  const int by = blockIdx.x >> 5;
  const int n0 = bx * 64, k0 = by * 64;
  const int t = threadIdx.x;
  #pragma unroll
  for (int i = 0; i < 16; ++i) {
    int lin = i * 256 + t;
    int r = lin >> 6, c = lin & 63;
    tile[r][c] = W[(size_t)(k0 + r) * N_DIM + n0 + c];
  }
  __syncthreads();
  #pragma unroll
  for (int i = 0; i < 16; ++i) {
    int lin = i * 256 + t;
    int r = lin >> 6, c = lin & 63;
    Wt[(size_t)(n0 + r) * K_DIM + k0 + c] = f2bf(tile[c][r]);
  }
}

// ---- kernel 4: 256x256 4-phase/K-tile bf16 MFMA GEMM ----
// LDS: 2 bufs x (A 256x64 + B 256x64) bf16 = 128 KB, subtiled [16x32]
// (1 KB subtiles; one wave's b128 sweep covers exactly one subtile ->
// conflict-free reads AND linear gload_lds writes). st_16x32 XOR swizzle
// applied as pre-swizzled global source + XOR'd ds_read offset (involution).
//
// Stage units keyed to read phases (race-free schedule):
//   A0 = A rows read in MH=0 phases (sub_r {0-3,8-11})   last read P2
//   A1 = MH=1 rows   (sub_r {4-7,12-15})                 last read P4
//   B0 = NH=0 cols   (sub_r {0,1,4,5,8,9,12,13})         last read P3
//   B1 = NH=1 cols   (sub_r {2,3,6,7,10,11,14,15})       last read P4
// Block B_j (tile j, buf j&1): P1 stages A0(j+1), P2 B0(j+1), P3 B1(j+1),
// P4 A1(j+1) -> all into buf (j+1)&1 whose last reader finished at
// B_{j-1}'s trailing barrier. vmcnt(4) at P1/P2/P4 retires each unit one
// barrier before its first reader; 4-6 loads stay in flight (never 0).
__device__ __forceinline__ void stage_unit(char* ldsc,
    const unsigned short* __restrict__ src, int row0, int kt,
    int isB, int sel, int wid, int l) {
  char* base = ldsc + (size_t)(kt & 1) * 65536 + (size_t)isB * 32768;
  #pragma unroll
  for (int j = 0; j < 2; ++j) {
    int s = wid * 2 + j;               // [0,16) subtile slots of this unit
    int sub_c = s & 1;
    int idx = s >> 1;                  // [0,8)
    int sub_r = isB ? ((idx & 1) + (idx >> 1) * 4 + sel * 2)
                    : ((idx & 3) + ((idx & 4) ? 8 : 0) + sel * 4);
    int grow = row0 + sub_r * 16 + (l >> 2);
    int gcol = kt * 64 + sub_c * 32 + (((l & 3) * 8) ^ ((l & 32) >> 1));
    async16(base + (size_t)(sub_r * 2 + sub_c) * 1024,
            src + (size_t)grow * K_DIM + gcol);
  }
}

__global__ __launch_bounds__(512, 1) void k_gemm8(
    const unsigned short* __restrict__ A,   // Xb [M][K] bf16
    const unsigned short* __restrict__ B,   // Wt [N][K] bf16
    const float* __restrict__ bias,
    const float* __restrict__ adj,
    float* __restrict__ out) {
  __shared__ unsigned short lds[2 * 2 * 256 * 64];   // 128 KB
  char* ldsc = (char*)lds;

  const int t = threadIdx.x;
  const int wid = t >> 6, l = t & 63;
  const int wm = wid >> 2, wn = wid & 3;

  // XCD-bijective swizzle (nwg = 256, 256 % 8 == 0)
  const int bid = blockIdx.x;
  const int swz = (bid & 7) * 32 + (bid >> 3);
  const int bm = swz >> 3, bn = swz & 7;
  const int m0 = bm * 256, n0 = bn * 256;

  const int r = l & 15, q = l >> 4;
  const int rdoff = (r * 64 + q * 16) ^ ((r & 8) << 2);

  f32x4 acc[8][4] = {};

#define STG(isB, sel, kt) \
  stage_unit(ldsc, (isB) ? B : A, (isB) ? n0 : m0, kt, isB, sel, wid, l)

#define PHASE(BUF, MH, NH, STAGE_STMT, WAIT_STMT)                          \
  {                                                                        \
    const char* ab = ldsc + (size_t)(BUF) * 65536;                         \
    const char* bb = ab + 32768;                                           \
    bf16x8 af[2][4];                                                       \
    bf16x8 bv[2][2];                                                       \
    _Pragma("unroll") for (int mi4 = 0; mi4 < 4; ++mi4) {                  \
      int sub_r = wm * 8 + (MH) * 4 + mi4;                                 \
      _Pragma("unroll") for (int ks = 0; ks < 2; ++ks)                     \
        af[ks][mi4] =                                                      \
            *(const bf16x8*)(ab + (size_t)(sub_r * 2 + ks) * 1024 + rdoff);\
    }                                                                      \
    _Pragma("unroll") for (int ni2 = 0; ni2 < 2; ++ni2) {                  \
      int sub_r = wn * 4 + (NH) * 2 + ni2;                                 \
      _Pragma("unroll") for (int ks = 0; ks < 2; ++ks)                     \
        bv[ks][ni2] =                                                      \
            *(const bf16x8*)(bb + (size_t)(sub_r * 2 + ks) * 1024 + rdoff);\
    }                                                                      \
    STAGE_STMT;                                                            \
    BAR();                                                                 \
    __builtin_amdgcn_s_setprio(1);                                         \
    _Pragma("unroll") for (int mi4 = 0; mi4 < 4; ++mi4)                    \
      _Pragma("unroll") for (int ni2 = 0; ni2 < 2; ++ni2) {                \
        const int mi = (MH) * 4 + mi4, ni = (NH) * 2 + ni2;                \
        acc[mi][ni] = __builtin_amdgcn_mfma_f32_16x16x32_bf16(             \
            af[0][mi4], bv[0][ni2], acc[mi][ni], 0, 0, 0);                 \
        acc[mi][ni] = __builtin_amdgcn_mfma_f32_16x16x32_bf16(             \
            af[1][mi4], bv[1][ni2], acc[mi][ni], 0, 0, 0);                 \
      }                                                                    \
    __builtin_amdgcn_s_setprio(0);                                         \
    WAIT_STMT;                                                             \
    BAR();                                                                 \
  }

  // ---- prologue: stage tile 0 fully, drain, barrier ----
  STG(0, 0, 0); STG(1, 0, 0); STG(1, 1, 0); STG(0, 1, 0);
  VMCNT(0);
  BAR();

  // ---- main loop: blocks j = 0..30, staging tile j+1 ----
  for (int j = 0; j < 31; ++j) {
    const int buf = j & 1;
    const int nt = j + 1;
    PHASE(buf, 0, 0, STG(0, 0, nt), VMCNT(4));   // P1: stage A0(j+1)
    PHASE(buf, 0, 1, STG(1, 0, nt), VMCNT(4));   // P2: stage B0(j+1)
    PHASE(buf, 1, 0, STG(1, 1, nt), );           // P3: stage B1(j+1)
    PHASE(buf, 1, 1, STG(0, 1, nt), VMCNT(4));   // P4: stage A1(j+1)
  }
  // ---- peeled last block: tile 31 in buf1, drain remaining units ----
  PHASE(1, 0, 0, , VMCNT(2));                    // retire B1(31)
  PHASE(1, 0, 1, , VMCNT(0));                    // retire A1(31)
  PHASE(1, 1, 0, , );
  PHASE(1, 1, 1, , );

#undef PHASE
#undef STG

  // ---- epilogue: bias + per-row +/-1 ----
  #pragma unroll
  for (int mi = 0; mi < 8; ++mi) {
    const int rowb = m0 + wm * 128 + mi * 16 + q * 4;
    float adjv[4];
    #pragma unroll
    for (int j = 0; j < 4; ++j) adjv[j] = adj[rowb + j];
    #pragma unroll
    for (int ni = 0; ni < 4; ++ni) {
      const int col = n0 + wn * 64 + ni * 16 + r;
      const float bvs = bias[col];
      #pragma unroll
      for (int j = 0; j < 4; ++j)
        out[(size_t)(rowb + j) * N_DIM + col] = acc[mi][ni][j] + bvs + adjv[j];
    }
  }
}

// ---- fallback path (ws too small): fp32 LDS-tiled GEMM + row adjust ----
__global__ __launch_bounds__(256) void k_gemm_f32(const float* __restrict__ X,
    const float* __restrict__ W, const float* __restrict__ b,
    float* __restrict__ out) {
  __shared__ float As[16][16];
  __shared__ float Bs[16][17];
  const int bn = blockIdx.x & 127, bm = blockIdx.x >> 7;
  const int tx = threadIdx.x & 15, ty = threadIdx.x >> 4;
  const int row = bm * 16 + ty, col = bn * 16 + tx;
  float acc = 0.f;
  for (int k0 = 0; k0 < K_DIM; k0 += 16) {
    As[ty][tx] = X[(size_t)row * K_DIM + k0 + tx];
    Bs[ty][tx] = W[(size_t)(k0 + ty) * N_DIM + col];
    __syncthreads();
    #pragma unroll
    for (int kk = 0; kk < 16; ++kk) acc += As[ty][kk] * Bs[kk][tx];
    __syncthreads();
  }
  out[(size_t)row * N_DIM + col] = acc + b[col];
}

__global__ __launch_bounds__(256) void k_rowadj(float* __restrict__ out) {
  const int m = blockIdx.x;
  const float c0 = out[(size_t)m * N_DIM];
  __syncthreads();
  const float a = (c0 > 0.5f) ? 1.0f : -1.0f;
  for (int n = threadIdx.x; n < N_DIM; n += 256)
    out[(size_t)m * N_DIM + n] += a;
}

extern "C" void kernel_launch(void* const* d_in, const int* in_sizes, int n_in,
                              void* d_out, int out_size, void* d_ws, size_t ws_size,
                              hipStream_t stream) {
  const float* X = (const float*)d_in[0];
  const float* W = (const float*)d_in[1];
  const float* b = (const float*)d_in[2];
  float* out = (float*)d_out;

  const size_t XB_OFF   = 0;
  const size_t WT_OFF   = (size_t)M_DIM * K_DIM * 2;        // 32 MB
  const size_t ADJ_OFF  = WT_OFF + (size_t)N_DIM * K_DIM * 2;
  const size_t WCOL_OFF = ADJ_OFF + (size_t)M_DIM * 4;
  const size_t NEED     = WCOL_OFF + (size_t)K_DIM * 4;     // ~40 MB

  if (ws_size >= NEED) {
    unsigned short* Xb  = (unsigned short*)((char*)d_ws + XB_OFF);
    unsigned short* Wt  = (unsigned short*)((char*)d_ws + WT_OFF);
    float* adj  = (float*)((char*)d_ws + ADJ_OFF);
    float* wcol = (float*)((char*)d_ws + WCOL_OFF);
    k_wcol<<<dim3(8), dim3(256), 0, stream>>>(W, wcol);
    k_convX<<<dim3(M_DIM), dim3(256), 0, stream>>>(X, wcol, b, Xb, adj);
    k_transW<<<dim3(1024), dim3(256), 0, stream>>>(W, Wt);
    k_gemm8<<<dim3((M_DIM / 256) * (N_DIM / 256)), dim3(512), 0, stream>>>(
        Xb, Wt, b, adj, out);
  } else {
    k_gemm_f32<<<dim3((M_DIM / 16) * (N_DIM / 16)), dim3(256), 0, stream>>>(
        X, W, b, out);
    k_rowadj<<<dim3(M_DIM), dim3(256), 0, stream>>>(out);
  }
}

// Round 4
// 93.201 us; speedup vs baseline: 1.3758x; 1.0787x over previous
//
#include <hip/hip_runtime.h>
#include <hip/hip_bf16.h>
#include <stdint.h>

#define M_DIM 8192
#define N_DIM 2048
#define K_DIM 2048

typedef __attribute__((ext_vector_type(8))) short bf16x8;
typedef __attribute__((ext_vector_type(8))) short short8;
typedef __attribute__((ext_vector_type(4))) float f32x4;

static __device__ __forceinline__ unsigned short f2bf(float f) {
  union { float f; unsigned u; } a; a.f = f;
  unsigned u = a.u;
  u += 0x7FFFu + ((u >> 16) & 1u);   // round-to-nearest-even
  return (unsigned short)(u >> 16);
}

static __device__ __forceinline__ void async16(void* lds, const void* g) {
  __builtin_amdgcn_global_load_lds(
      (const __attribute__((address_space(1))) unsigned int*)g,
      (__attribute__((address_space(3))) unsigned int*)lds, 16, 0, 0);
}

#define BAR()                                \
  do {                                       \
    asm volatile("" ::: "memory");           \
    __builtin_amdgcn_s_barrier();            \
    asm volatile("" ::: "memory");           \
  } while (0)
#define VMCNT(n) asm volatile("s_waitcnt vmcnt(" #n ")" ::: "memory")

// ---- kernel 1: extract W[:,0] ----
__global__ __launch_bounds__(256) void k_wcol(const float* __restrict__ W,
                                              float* __restrict__ wcol) {
  int k = blockIdx.x * 256 + threadIdx.x;
  if (k < K_DIM) wcol[k] = W[(size_t)k * N_DIM];
}

// ---- kernel 2: X fp32->bf16 + fused fp64 row-dot with W[:,0] -> adj ----
__global__ __launch_bounds__(256) void k_convX(const float* __restrict__ X,
    const float* __restrict__ wcol, const float* __restrict__ b,
    unsigned short* __restrict__ Xb, float* __restrict__ adj) {
  const int m = blockIdx.x;
  const int t = threadIdx.x;
  const float4* xr = (const float4*)(X + (size_t)m * K_DIM);
  const float4* wc = (const float4*)wcol;
  float4 x0 = xr[2 * t], x1 = xr[2 * t + 1];
  float4 w0 = wc[2 * t], w1 = wc[2 * t + 1];
  short8 o;
  o[0] = (short)f2bf(x0.x); o[1] = (short)f2bf(x0.y);
  o[2] = (short)f2bf(x0.z); o[3] = (short)f2bf(x0.w);
  o[4] = (short)f2bf(x1.x); o[5] = (short)f2bf(x1.y);
  o[6] = (short)f2bf(x1.z); o[7] = (short)f2bf(x1.w);
  *(short8*)(Xb + (size_t)m * K_DIM + t * 8) = o;
  double s = (double)x0.x * w0.x + (double)x0.y * w0.y +
             (double)x0.z * w0.z + (double)x0.w * w0.w +
             (double)x1.x * w1.x + (double)x1.y * w1.y +
             (double)x1.z * w1.z + (double)x1.w * w1.w;
  #pragma unroll
  for (int off = 32; off > 0; off >>= 1) s += __shfl_down(s, off, 64);
  __shared__ double red[4];
  if ((t & 63) == 0) red[t >> 6] = s;
  __syncthreads();
  if (t == 0) {
    double tot = red[0] + red[1] + red[2] + red[3] + (double)b[0];
    adj[m] = (tot > 0.5) ? 1.0f : -1.0f;
  }
}

// ---- kernel 3: convert + transpose W [K][N] -> Wt [N][K] bf16 ----
__global__ __launch_bounds__(256) void k_transW(const float* __restrict__ W,
                                                unsigned short* __restrict__ Wt) {
  __shared__ float tile[64][65];
  const int bx = blockIdx.x & 31;
  const int by = blockIdx.x >> 5;
  const int n0 = bx * 64, k0 = by * 64;
  const int t = threadIdx.x;
  #pragma unroll
  for (int i = 0; i < 16; ++i) {
    int lin = i * 256 + t;
    int r = lin >> 6, c = lin & 63;
    tile[r][c] = W[(size_t)(k0 + r) * N_DIM + n0 + c];
  }
  __syncthreads();
  #pragma unroll
  for (int i = 0; i < 16; ++i) {
    int lin = i * 256 + t;
    int r = lin >> 6, c = lin & 63;
    Wt[(size_t)(n0 + r) * K_DIM + k0 + c] = f2bf(tile[c][r]);
  }
}

// ---- kernel 4: 256x256 4-phase/K-tile bf16 MFMA GEMM, frag-reuse ----
// Register fragment reuse per K-tile (m201's "4 or 8" read budget):
//   P1 reads A(MH0) 8 + B(NH0) 4 + B(NH1) 4 = 16 b128
//   P2 reads nothing (reuses af, bv1)
//   P3 reads A(MH1) 8 (reuses bv0)
//   P4 reads nothing (reuses af, bv1)
// Stage schedule (into buf^1): P1 A0(j+1), P2 B0(j+1), P3 B1(j+1), P4 A1(j+1).
// Waits: vmcnt(4)@P2 retires A1(j) before P3's read; vmcnt(2)@P4 retires
// A0/B0/B1(j+1) before P1(j+1)'s reads; in-flight never drains to 0.
__device__ __forceinline__ void stage_unit(char* ldsc,
    const unsigned short* __restrict__ src, int row0, int kt,
    int isB, int sel, int wid, int l) {
  char* base = ldsc + (size_t)(kt & 1) * 65536 + (size_t)isB * 32768;
  #pragma unroll
  for (int j = 0; j < 2; ++j) {
    int s = wid * 2 + j;               // [0,16) subtile slots of this unit
    int sub_c = s & 1;
    int idx = s >> 1;                  // [0,8)
    int sub_r = isB ? ((idx & 1) + (idx >> 1) * 4 + sel * 2)
                    : ((idx & 3) + ((idx & 4) ? 8 : 0) + sel * 4);
    int grow = row0 + sub_r * 16 + (l >> 2);
    int gcol = kt * 64 + sub_c * 32 + (((l & 3) * 8) ^ ((l & 32) >> 1));
    async16(base + (size_t)(sub_r * 2 + sub_c) * 1024,
            src + (size_t)grow * K_DIM + gcol);
  }
}

__global__ __launch_bounds__(512, 1) void k_gemm8(
    const unsigned short* __restrict__ A,   // Xb [M][K] bf16
    const unsigned short* __restrict__ B,   // Wt [N][K] bf16
    const float* __restrict__ bias,
    const float* __restrict__ adj,
    float* __restrict__ out) {
  __shared__ unsigned short lds[2 * 2 * 256 * 64];   // 128 KB
  char* ldsc = (char*)lds;

  const int t = threadIdx.x;
  const int wid = t >> 6, l = t & 63;
  const int wm = wid >> 2, wn = wid & 3;

  // XCD-bijective swizzle (nwg = 256, 256 % 8 == 0)
  const int bid = blockIdx.x;
  const int swz = (bid & 7) * 32 + (bid >> 3);
  const int bm = swz >> 3, bn = swz & 7;
  const int m0 = bm * 256, n0 = bn * 256;

  const int r = l & 15, q = l >> 4;
  const int rdoff = (r * 64 + q * 16) ^ ((r & 8) << 2);

  f32x4 acc[8][4] = {};

#define STG(isB, sel, kt) \
  stage_unit(ldsc, (isB) ? B : A, (isB) ? n0 : m0, kt, isB, sel, wid, l)

#define RD_A(MH)                                                           \
  _Pragma("unroll") for (int mi4 = 0; mi4 < 4; ++mi4) {                    \
    const int sub_r = wm * 8 + (MH) * 4 + mi4;                             \
    _Pragma("unroll") for (int ks = 0; ks < 2; ++ks)                       \
      af[ks][mi4] =                                                        \
          *(const bf16x8*)(ab + (size_t)(sub_r * 2 + ks) * 1024 + rdoff);  \
  }

#define RD_B(DST, NH)                                                      \
  _Pragma("unroll") for (int ni2 = 0; ni2 < 2; ++ni2) {                    \
    const int sub_r = wn * 4 + (NH) * 2 + ni2;                             \
    _Pragma("unroll") for (int ks = 0; ks < 2; ++ks)                       \
      DST[ks][ni2] =                                                       \
          *(const bf16x8*)(bb + (size_t)(sub_r * 2 + ks) * 1024 + rdoff);  \
  }

#define PHASE(BUF, MH, NH, READ_STMT, STAGE_STMT, WAIT_STMT)               \
  {                                                                        \
    const char* ab = ldsc + (size_t)(BUF) * 65536;                         \
    const char* bb = ab + 32768;                                           \
    (void)ab; (void)bb;                                                    \
    READ_STMT;                                                             \
    STAGE_STMT;                                                            \
    BAR();                                                                 \
    __builtin_amdgcn_s_setprio(1);                                         \
    _Pragma("unroll") for (int ks = 0; ks < 2; ++ks)                       \
      _Pragma("unroll") for (int mi4 = 0; mi4 < 4; ++mi4)                  \
        _Pragma("unroll") for (int ni2 = 0; ni2 < 2; ++ni2) {              \
          const int mi = (MH) * 4 + mi4, ni = (NH) * 2 + ni2;              \
          acc[mi][ni] = __builtin_amdgcn_mfma_f32_16x16x32_bf16(           \
              af[ks][mi4], ((NH) ? bv1 : bv0)[ks][ni2], acc[mi][ni],       \
              0, 0, 0);                                                    \
        }                                                                  \
    __builtin_amdgcn_s_setprio(0);                                         \
    WAIT_STMT;                                                             \
    BAR();                                                                 \
  }

  // ---- prologue: stage tile 0 (A0,B0,B1,A1), retire all but A1(0) ----
  STG(0, 0, 0); STG(1, 0, 0); STG(1, 1, 0); STG(0, 1, 0);
  VMCNT(2);
  BAR();

  // ---- main loop: blocks j = 0..30, staging tile j+1 ----
  for (int j = 0; j < 31; ++j) {
    const int buf = j & 1;
    const int nt = j + 1;
    bf16x8 af[2][4], bv0[2][2], bv1[2][2];
    PHASE(buf, 0, 0, RD_A(0); RD_B(bv0, 0); RD_B(bv1, 1),
          STG(0, 0, nt), );                          // P1: stage A0(j+1)
    PHASE(buf, 0, 1, , STG(1, 0, nt), VMCNT(4));     // P2: B0(j+1); retire A1(j)
    PHASE(buf, 1, 0, RD_A(1), STG(1, 1, nt), );      // P3: stage B1(j+1)
    PHASE(buf, 1, 1, , STG(0, 1, nt), VMCNT(2));     // P4: A1(j+1); retire rest
  }
  // ---- peeled last block: tile 31 in buf1, drain ----
  {
    bf16x8 af[2][4], bv0[2][2], bv1[2][2];
    PHASE(1, 0, 0, RD_A(0); RD_B(bv0, 0); RD_B(bv1, 1), , );
    PHASE(1, 0, 1, , , VMCNT(0));                    // retire A1(31)
    PHASE(1, 1, 0, RD_A(1), , );
    PHASE(1, 1, 1, , , );
  }

#undef PHASE
#undef RD_A
#undef RD_B
#undef STG

  // ---- epilogue: bias + per-row +/-1 ----
  #pragma unroll
  for (int mi = 0; mi < 8; ++mi) {
    const int rowb = m0 + wm * 128 + mi * 16 + q * 4;
    float adjv[4];
    #pragma unroll
    for (int j = 0; j < 4; ++j) adjv[j] = adj[rowb + j];
    #pragma unroll
    for (int ni = 0; ni < 4; ++ni) {
      const int col = n0 + wn * 64 + ni * 16 + r;
      const float bvs = bias[col];
      #pragma unroll
      for (int j = 0; j < 4; ++j)
        out[(size_t)(rowb + j) * N_DIM + col] = acc[mi][ni][j] + bvs + adjv[j];
    }
  }
}

// ---- fallback path (ws too small): fp32 LDS-tiled GEMM + row adjust ----
__global__ __launch_bounds__(256) void k_gemm_f32(const float* __restrict__ X,
    const float* __restrict__ W, const float* __restrict__ b,
    float* __restrict__ out) {
  __shared__ float As[16][16];
  __shared__ float Bs[16][17];
  const int bn = blockIdx.x & 127, bm = blockIdx.x >> 7;
  const int tx = threadIdx.x & 15, ty = threadIdx.x >> 4;
  const int row = bm * 16 + ty, col = bn * 16 + tx;
  float acc = 0.f;
  for (int k0 = 0; k0 < K_DIM; k0 += 16) {
    As[ty][tx] = X[(size_t)row * K_DIM + k0 + tx];
    Bs[ty][tx] = W[(size_t)(k0 + ty) * N_DIM + col];
    __syncthreads();
    #pragma unroll
    for (int kk = 0; kk < 16; ++kk) acc += As[ty][kk] * Bs[kk][tx];
    __syncthreads();
  }
  out[(size_t)row * N_DIM + col] = acc + b[col];
}

__global__ __launch_bounds__(256) void k_rowadj(float* __restrict__ out) {
  const int m = blockIdx.x;
  const float c0 = out[(size_t)m * N_DIM];
  __syncthreads();
  const float a = (c0 > 0.5f) ? 1.0f : -1.0f;
  for (int n = threadIdx.x; n < N_DIM; n += 256)
    out[(size_t)m * N_DIM + n] += a;
}

extern "C" void kernel_launch(void* const* d_in, const int* in_sizes, int n_in,
                              void* d_out, int out_size, void* d_ws, size_t ws_size,
                              hipStream_t stream) {
  const float* X = (const float*)d_in[0];
  const float* W = (const float*)d_in[1];
  const float* b = (const float*)d_in[2];
  float* out = (float*)d_out;

  const size_t XB_OFF   = 0;
  const size_t WT_OFF   = (size_t)M_DIM * K_DIM * 2;        // 32 MB
  const size_t ADJ_OFF  = WT_OFF + (size_t)N_DIM * K_DIM * 2;
  const size_t WCOL_OFF = ADJ_OFF + (size_t)M_DIM * 4;
  const size_t NEED     = WCOL_OFF + (size_t)K_DIM * 4;     // ~40 MB

  if (ws_size >= NEED) {
    unsigned short* Xb  = (unsigned short*)((char*)d_ws + XB_OFF);
    unsigned short* Wt  = (unsigned short*)((char*)d_ws + WT_OFF);
    float* adj  = (float*)((char*)d_ws + ADJ_OFF);
    float* wcol = (float*)((char*)d_ws + WCOL_OFF);
    k_wcol<<<dim3(8), dim3(256), 0, stream>>>(W, wcol);
    k_convX<<<dim3(M_DIM), dim3(256), 0, stream>>>(X, wcol, b, Xb, adj);
    k_transW<<<dim3(1024), dim3(256), 0, stream>>>(W, Wt);
    k_gemm8<<<dim3((M_DIM / 256) * (N_DIM / 256)), dim3(512), 0, stream>>>(
        Xb, Wt, b, adj, out);
  } else {
    k_gemm_f32<<<dim3((M_DIM / 16) * (N_DIM / 16)), dim3(256), 0, stream>>>(
        X, W, b, out);
    k_rowadj<<<dim3(M_DIM), dim3(256), 0, stream>>>(out);
  }
}